// Round 1
// baseline (142.733 us; speedup 1.0000x reference)
//
#include <hip/hip_runtime.h>
#include <hip/hip_bf16.h>

// Chamfer distance: B=8, N=M=4096, D=128, fp32 inputs, scalar fp32 out.
// dist[b,n,m] = ||p1||^2 + ||p2||^2 - 2*p1.p2  (cross via bf16 MFMA GEMM)
// out = mean_n(min_m dist) + mean_m(min_n dist)

#define BATCH 8
#define NPTS 4096
#define DIM 128

using bf16x8 = __attribute__((ext_vector_type(8))) short;
using f32x4  = __attribute__((ext_vector_type(4))) float;

// ---------------- K1: fp32 -> bf16 + exact fp32 squared norms ----------------
__global__ void prep_kernel(const float* __restrict__ src,
                            __hip_bfloat16* __restrict__ dst,
                            float* __restrict__ sq) {
    const int wid = threadIdx.x >> 6;
    const int l   = threadIdx.x & 63;
    const int p   = blockIdx.x * 4 + wid;   // one wave per point
    const float2 v = *reinterpret_cast<const float2*>(src + (size_t)p * DIM + l * 2);
    __hip_bfloat162 h = __float22bfloat162_rn(v);
    *reinterpret_cast<__hip_bfloat162*>(dst + (size_t)p * DIM + l * 2) = h;
    float s = v.x * v.x + v.y * v.y;
    #pragma unroll
    for (int off = 1; off < 64; off <<= 1) s += __shfl_xor(s, off);
    if (l == 0) sq[p] = s;
}

// ---------------- K2: tiled GEMM + fused directional mins --------------------
// grid (32 n-tiles, 2 m-halves, 8 batches), 256 threads (4 waves).
// Block owns 128 rows (wave: 32 rows), loops over 16 m-tiles of 128 cols.
__global__ void __launch_bounds__(256, 2)
chamfer_tile_kernel(const __hip_bfloat16* __restrict__ bf1,
                    const __hip_bfloat16* __restrict__ bf2,
                    const float* __restrict__ sq1,
                    const float* __restrict__ sq2,
                    float* __restrict__ min1p,   // [B][2][NPTS]  (sq2 - 2c) row-mins
                    float* __restrict__ min2p) { // [B][32][NPTS] (sq1 - 2c) col-mins
    const int nt = blockIdx.x;      // n-tile (128 rows)
    const int mh = blockIdx.y;      // m half (2048 cols)
    const int b  = blockIdx.z;
    const int tid = threadIdx.x;
    const int wid = tid >> 6;
    const int l   = tid & 63;
    const int l15 = l & 15;
    const int lhi = l >> 4;

    __shared__ __align__(16) unsigned char btile[128 * 256]; // 128 rows x 256B (bf16)
    __shared__ float colminbuf[4][128];
    __shared__ float sq2b[128];

    const __hip_bfloat16* bf1b = bf1 + (size_t)b * NPTS * DIM;
    const __hip_bfloat16* bf2b = bf2 + (size_t)b * NPTS * DIM;

    const int n0 = nt * 128 + wid * 32;  // wave's first row

    // A fragments: rows n0 + rt*16 + l15, k = ks*32 + lhi*8 (8 contiguous bf16)
    bf16x8 afrag[2][4];
    #pragma unroll
    for (int rt = 0; rt < 2; ++rt)
        #pragma unroll
        for (int ks = 0; ks < 4; ++ks)
            afrag[rt][ks] = *reinterpret_cast<const bf16x8*>(
                bf1b + (n0 + rt * 16 + l15) * DIM + ks * 32 + lhi * 8);

    // sq1 values for the accumulator rows: n0 + rt*16 + lhi*4 + j
    float sq1v[2][4];
    #pragma unroll
    for (int rt = 0; rt < 2; ++rt)
        #pragma unroll
        for (int j = 0; j < 4; ++j)
            sq1v[rt][j] = sq1[b * NPTS + n0 + rt * 16 + lhi * 4 + j];

    float rmin[2][4];
    #pragma unroll
    for (int rt = 0; rt < 2; ++rt)
        #pragma unroll
        for (int j = 0; j < 4; ++j) rmin[rt][j] = 3.4e38f;

    for (int mt = 0; mt < 16; ++mt) {
        const int m0 = mh * 2048 + mt * 128;

        __syncthreads(); // protect btile/colminbuf from previous iteration reads

        // stage B tile (128 rows x 128 bf16) with XOR swizzle; 8 x 16B per thread
        #pragma unroll
        for (int i = 0; i < 8; ++i) {
            const int c = i * 256 + tid;
            const int row = c >> 4;
            const int q   = c & 15;
            bf16x8 v = *reinterpret_cast<const bf16x8*>(
                bf2b + (m0 + row) * DIM + q * 8);
            const int dst = row * 256 + ((q * 16) ^ ((row & 7) << 4));
            *reinterpret_cast<bf16x8*>(&btile[dst]) = v;
        }
        if (tid < 128) sq2b[tid] = sq2[b * NPTS + m0 + tid];
        __syncthreads();

        // MFMA: acc[rt][ct] = P1rows x P2rows^T, K=128
        f32x4 acc[2][8];
        #pragma unroll
        for (int rt = 0; rt < 2; ++rt)
            #pragma unroll
            for (int ct = 0; ct < 8; ++ct) acc[rt][ct] = f32x4{0.f, 0.f, 0.f, 0.f};

        #pragma unroll
        for (int ks = 0; ks < 4; ++ks) {
            #pragma unroll
            for (int ct = 0; ct < 8; ++ct) {
                const int brow = ct * 16 + l15;
                const int kbyte = ks * 64 + lhi * 16;
                bf16x8 bfrag = *reinterpret_cast<const bf16x8*>(
                    &btile[brow * 256 + (kbyte ^ ((brow & 7) << 4))]);
                #pragma unroll
                for (int rt = 0; rt < 2; ++rt)
                    acc[rt][ct] = __builtin_amdgcn_mfma_f32_16x16x32_bf16(
                        afrag[rt][ks], bfrag, acc[rt][ct], 0, 0, 0);
            }
        }

        // epilogue: fold into row-mins (registers) and col-mins (partial)
        float cmin[8];
        #pragma unroll
        for (int ct = 0; ct < 8; ++ct) cmin[ct] = 3.4e38f;

        #pragma unroll
        for (int rt = 0; rt < 2; ++rt) {
            #pragma unroll
            for (int ct = 0; ct < 8; ++ct) {
                const float s2 = sq2b[ct * 16 + l15];
                #pragma unroll
                for (int j = 0; j < 4; ++j) {
                    const float c2 = acc[rt][ct][j] + acc[rt][ct][j];
                    rmin[rt][j] = fminf(rmin[rt][j], s2 - c2);
                    cmin[ct]    = fminf(cmin[ct], sq1v[rt][j] - c2);
                }
            }
        }

        // col-min: reduce across the 4 row-groups (lane bits 4,5)
        #pragma unroll
        for (int ct = 0; ct < 8; ++ct) {
            cmin[ct] = fminf(cmin[ct], __shfl_xor(cmin[ct], 16));
            cmin[ct] = fminf(cmin[ct], __shfl_xor(cmin[ct], 32));
        }
        if (l < 16) {
            #pragma unroll
            for (int ct = 0; ct < 8; ++ct) colminbuf[wid][ct * 16 + l] = cmin[ct];
        }
        __syncthreads();
        if (tid < 128) {
            float v = fminf(fminf(colminbuf[0][tid], colminbuf[1][tid]),
                            fminf(colminbuf[2][tid], colminbuf[3][tid]));
            min2p[((size_t)b * 32 + nt) * NPTS + m0 + tid] = v;
        }
    }

    // row-min: reduce across lane bits 0..3 (cols), then write once per row
    #pragma unroll
    for (int rt = 0; rt < 2; ++rt)
        #pragma unroll
        for (int j = 0; j < 4; ++j) {
            float v = rmin[rt][j];
            v = fminf(v, __shfl_xor(v, 1));
            v = fminf(v, __shfl_xor(v, 2));
            v = fminf(v, __shfl_xor(v, 4));
            v = fminf(v, __shfl_xor(v, 8));
            rmin[rt][j] = v;
        }
    if (l15 == 0) {
        #pragma unroll
        for (int rt = 0; rt < 2; ++rt)
            #pragma unroll
            for (int j = 0; j < 4; ++j)
                min1p[((size_t)b * 2 + mh) * NPTS + n0 + rt * 16 + lhi * 4 + j] =
                    rmin[rt][j];
    }
}

// ---------------- K3: combine partials, means, scalar out --------------------
__global__ void finalize_kernel(const float* __restrict__ min1p,
                                const float* __restrict__ min2p,
                                const float* __restrict__ sq1,
                                const float* __restrict__ sq2,
                                float* __restrict__ out) {
    const int tid = threadIdx.x;
    const int gid = blockIdx.x * 256 + tid;
    float sum = 0.f;

    for (int idx = gid; idx < BATCH * NPTS; idx += 64 * 256) {
        const int b = idx >> 12, n = idx & (NPTS - 1);
        const float v = fminf(min1p[(b * 2 + 0) * NPTS + n],
                              min1p[(b * 2 + 1) * NPTS + n]) + sq1[idx];
        sum += v;
    }
    for (int idx = gid; idx < BATCH * NPTS; idx += 64 * 256) {
        const int b = idx >> 12, m = idx & (NPTS - 1);
        float v = 3.4e38f;
        for (int nt = 0; nt < 32; ++nt)
            v = fminf(v, min2p[((size_t)b * 32 + nt) * NPTS + m]);
        sum += v + sq2[idx];
    }

    #pragma unroll
    for (int off = 1; off < 64; off <<= 1) sum += __shfl_xor(sum, off);
    __shared__ float wsum[4];
    if ((tid & 63) == 0) wsum[tid >> 6] = sum;
    __syncthreads();
    if (tid == 0) {
        const float t = wsum[0] + wsum[1] + wsum[2] + wsum[3];
        atomicAdd(out, t * (1.0f / (BATCH * NPTS)));
    }
}

extern "C" void kernel_launch(void* const* d_in, const int* in_sizes, int n_in,
                              void* d_out, int out_size, void* d_ws, size_t ws_size,
                              hipStream_t stream) {
    const float* p1 = (const float*)d_in[0];
    const float* p2 = (const float*)d_in[1];
    float* out = (float*)d_out;

    const size_t npts_tot = (size_t)BATCH * NPTS;          // 32768 points/array
    __hip_bfloat16* bf1 = (__hip_bfloat16*)d_ws;
    __hip_bfloat16* bf2 = bf1 + npts_tot * DIM;
    float* sq1   = (float*)(bf2 + npts_tot * DIM);
    float* sq2   = sq1 + npts_tot;
    float* min1p = sq2 + npts_tot;                         // [B][2][NPTS]
    float* min2p = min1p + (size_t)BATCH * 2 * NPTS;       // [B][32][NPTS]

    hipMemsetAsync(d_out, 0, sizeof(float), stream);

    prep_kernel<<<npts_tot / 4, 256, 0, stream>>>(p1, bf1, sq1);
    prep_kernel<<<npts_tot / 4, 256, 0, stream>>>(p2, bf2, sq2);

    dim3 g2(32, 2, BATCH);
    chamfer_tile_kernel<<<g2, 256, 0, stream>>>(bf1, bf2, sq1, sq2, min1p, min2p);

    finalize_kernel<<<64, 256, 0, stream>>>(min1p, min2p, sq1, sq2, out);
}